// Round 1
// 1760.035 us; speedup vs baseline: 2.1060x; 2.1060x over previous
//
#include <hip/hip_runtime.h>
#include <cstdint>
#include <cstddef>

typedef __bf16 bf16;
typedef __bf16 bf16x8 __attribute__((ext_vector_type(8)));
typedef __bf16 bf16x4 __attribute__((ext_vector_type(4)));
typedef float  f32x4  __attribute__((ext_vector_type(4)));

#define D_MODEL 512
#define D_INNER 1024
#define D_STATE 16
#define D_CONV  4
#define DT_RANK 32
#define N_LAYER 4
#define H_FFN   2048
#define SEQ_T   1024
#define BATCH   2
#define BT      (BATCH * SEQ_T)   // 2048 tokens
#define VOCAB   32000

// chunked scan parameters
#define NCHUNK  16
#define CHUNK   (SEQ_T / NCHUNK)  // 64

__device__ __forceinline__ float b2f(bf16 x) { return (float)x; }
__device__ __forceinline__ bf16  f2b(float x) { return (bf16)x; }

// dual-dtype scalar read: p holds bf16 if bf!=0 else f32
__device__ __forceinline__ float rdf(const void* p, long i, int bf) {
  return bf ? (float)((const bf16*)p)[i] : ((const float*)p)[i];
}

__device__ __forceinline__ void async16(const void* g, void* l) {
  __builtin_amdgcn_global_load_lds((const __attribute__((address_space(1))) void*)g,
                                   (__attribute__((address_space(3))) void*)l, 16, 0, 0);
}

// ---------------------------------------------------------------------------
// dtype probe: if inputs are f32, bf16-view words at even indices are mantissa
// fragments -> random exponent -> some |x| >= 128 with certainty over 512
// words. Real bf16 data here is |x| <= ~0.2.  flag=1 -> inputs are bf16.
// ---------------------------------------------------------------------------
__global__ void probe_k(const unsigned short* __restrict__ tok,
                        const unsigned short* __restrict__ pos,
                        int* __restrict__ flag)
{
  int lane = threadIdx.x;
  int bad = 0;
  for (int i = lane; i < 512; i += 64) {
    int e0 = (tok[i] >> 7) & 0xFF;
    int e1 = (pos[i] >> 7) & 0xFF;
    if (e0 >= 134 || e1 >= 134) bad = 1;   // |v|>=128 or inf/nan
  }
  unsigned long long m = __ballot(bad);
  if (lane == 0) *flag = (m == 0ULL) ? 1 : 0;
}

// f32 -> bf16 arena conversion (no-op when inputs are already bf16)
__global__ __launch_bounds__(256) void cvt_k(const float4* __restrict__ src,
                                             bf16* __restrict__ dst,
                                             int n4, const int* __restrict__ dflag)
{
  if (*dflag) return;
  int i = blockIdx.x * 256 + threadIdx.x;
  if (i >= n4) return;
  float4 v = src[i];
  bf16x4 o; o[0] = f2b(v.x); o[1] = f2b(v.y); o[2] = f2b(v.z); o[3] = f2b(v.w);
  *(bf16x4*)(dst + (size_t)i * 4) = o;
}

// ---------------------------------------------------------------------------
// NT GEMM: C[M,N] = A[M,K] * B[N,K]^T. A: bf16 (internal). B: canonical bf16
// arena (flag=0) or raw d_in read as bf16 (flag=1). 128x128 tile, BK=32,
// 4 waves, mfma_f32_16x16x32_bf16, global_load_lds width-16 staging.
// OUTMODE: 0=f32, 1=bf16, 2=select by flag (final logits).
// ---------------------------------------------------------------------------
template<int OUTMODE, bool RELU>
__global__ __launch_bounds__(256) void gemm_nt(
    const bf16* __restrict__ A, const bf16* __restrict__ Barena,
    const void* __restrict__ Braw, long boff,
    void* __restrict__ Cout, const void* __restrict__ bias, long biasoff,
    const float* __restrict__ res, const int* __restrict__ dflag,
    int M, int N, int K)
{
  __shared__ __attribute__((aligned(16))) bf16 As[128 * 32];
  __shared__ __attribute__((aligned(16))) bf16 Bs[128 * 32];

  const int bf = *dflag;
  const bf16* Bw = bf ? ((const bf16*)Braw + boff) : Barena;

  const int tid  = threadIdx.x;
  const int lane = tid & 63;
  const int q    = lane >> 4;     // quad 0..3
  const int m16  = lane & 15;
  const int w    = tid >> 6;      // wave 0..3
  const int wr   = w >> 1, wc = w & 1;   // 2x2 wave grid, 64x64 per wave

  const int rowA0 = blockIdx.y * 128;   // M-tile base
  const int rowB0 = blockIdx.x * 128;   // N-tile base

  f32x4 acc[4][4] = {};

  for (int k0 = 0; k0 < K; k0 += 32) {
    // stage A-tile and B-tile (128x32 bf16 each) as 512 16B chunks / tile.
    // chunk ci -> LDS bytes [ci*16, ci*16+16): row = ci>>2, k-chunk = ci&3.
    // LDS base is wave-uniform (tid & 192 == wave*64); HW scatters lane*16.
#pragma unroll
    for (int r = 0; r < 2; r++) {
      int ci  = r * 256 + tid;
      int row = ci >> 2;
      int kc  = ci & 3;
      const bf16* ga = A  + (size_t)(rowA0 + row) * K + (k0 + kc * 8);
      const bf16* gb = Bw + (size_t)(rowB0 + row) * K + (k0 + kc * 8);
      char* la = (char*)As + (size_t)(r * 256 + (tid & 192)) * 16;
      char* lb = (char*)Bs + (size_t)(r * 256 + (tid & 192)) * 16;
      async16(ga, la);
      async16(gb, lb);
    }
    __syncthreads();

    bf16x8 af[4], bfr[4];
#pragma unroll
    for (int mt = 0; mt < 4; mt++)
      af[mt] = *(const bf16x8*)&As[(wr * 64 + mt * 16 + m16) * 32 + q * 8];
#pragma unroll
    for (int nt = 0; nt < 4; nt++)
      bfr[nt] = *(const bf16x8*)&Bs[(wc * 64 + nt * 16 + m16) * 32 + q * 8];

#pragma unroll
    for (int mt = 0; mt < 4; mt++)
#pragma unroll
      for (int nt = 0; nt < 4; nt++)
        acc[mt][nt] = __builtin_amdgcn_mfma_f32_16x16x32_bf16(
            af[mt], bfr[nt], acc[mt][nt], 0, 0, 0);

    __syncthreads();
  }

  // epilogue: C/D layout col = lane&15, row = quad*4 + reg  [m89/m91]
#pragma unroll
  for (int mt = 0; mt < 4; mt++) {
#pragma unroll
    for (int r = 0; r < 4; r++) {
      int row = rowA0 + wr * 64 + mt * 16 + q * 4 + r;
#pragma unroll
      for (int nt = 0; nt < 4; nt++) {
        int col = rowB0 + wc * 64 + nt * 16 + m16;
        float v = acc[mt][nt][r];
        if (bias) v += rdf(bias, biasoff + col, bf);
        if (res)  v += res[(size_t)row * N + col];
        if (RELU) v = fmaxf(v, 0.f);
        size_t oi = (size_t)row * N + col;
        if (OUTMODE == 1 || (OUTMODE == 2 && bf)) ((bf16*)Cout)[oi] = f2b(v);
        else                                      ((float*)Cout)[oi] = v;
      }
    }
  }
}

// ---------------------------------------------------------------------------
// x[bt,:] = tok_emb[idx[bt],:] + pos_emb[t,:]   (dual-dtype reads, f32 out)
// ---------------------------------------------------------------------------
__global__ void embed_k(const int* __restrict__ idx, const void* __restrict__ tok,
                        const void* __restrict__ pos, float* __restrict__ x,
                        const int* __restrict__ dflag)
{
  int bf = *dflag;
  int bt = blockIdx.x;
  int t  = bt & (SEQ_T - 1);
  long rowv = idx[bt];
  for (int i = threadIdx.x; i < D_MODEL; i += blockDim.x)
    x[(size_t)bt * D_MODEL + i] = rdf(tok, rowv * D_MODEL + i, bf)
                                + rdf(pos, (long)t * D_MODEL + i, bf);
}

// ---------------------------------------------------------------------------
// LayerNorm over D_MODEL=512, one wave per row. f32 in, bf16 out.
// ---------------------------------------------------------------------------
__global__ __launch_bounds__(64) void ln_k(const float* __restrict__ x,
                                           const void* __restrict__ g,
                                           const void* __restrict__ bb,
                                           long goff,
                                           bf16* __restrict__ out,
                                           const int* __restrict__ dflag)
{
  int bf = *dflag;
  int row = blockIdx.x;
  const float4* xr = (const float4*)(x + (size_t)row * D_MODEL);
  int l = threadIdx.x;
  float4 v0 = xr[l];
  float4 v1 = xr[64 + l];
  float s  = (v0.x + v0.y) + (v0.z + v0.w) + (v1.x + v1.y) + (v1.z + v1.w);
  float ss = v0.x*v0.x + v0.y*v0.y + v0.z*v0.z + v0.w*v0.w
           + v1.x*v1.x + v1.y*v1.y + v1.z*v1.z + v1.w*v1.w;
#pragma unroll
  for (int o = 32; o; o >>= 1) { s += __shfl_xor(s, o); ss += __shfl_xor(ss, o); }
  float m   = s  * (1.f / 512.f);
  float var = ss * (1.f / 512.f) - m * m;
  float inv = rsqrtf(var + 1e-5f);
  float vs[8] = {v0.x, v0.y, v0.z, v0.w, v1.x, v1.y, v1.z, v1.w};
  int i0 = l * 4, i1 = 256 + l * 4;
#pragma unroll
  for (int e = 0; e < 4; e++) {
    out[(size_t)row * D_MODEL + i0 + e] =
        f2b((vs[e] - m) * inv * rdf(g, goff + i0 + e, bf) + rdf(bb, goff + i0 + e, bf));
    out[(size_t)row * D_MODEL + i1 + e] =
        f2b((vs[4 + e] - m) * inv * rdf(g, goff + i1 + e, bf) + rdf(bb, goff + i1 + e, bf));
  }
}

// ---------------------------------------------------------------------------
// causal depthwise conv (DC=4) over u-half of xz (f32), + bias, SiLU -> bf16 u
// ---------------------------------------------------------------------------
__global__ __launch_bounds__(256) void conv_silu_k(const float* __restrict__ xz,
                                                   const void* __restrict__ cw,
                                                   const void* __restrict__ cb,
                                                   long cwoff, long cboff,
                                                   bf16* __restrict__ u,
                                                   const int* __restrict__ dflag)
{
  int bf  = *dflag;
  int gid = blockIdx.x * 256 + threadIdx.x;
  int d   = gid & (D_INNER - 1);
  int bt  = gid >> 10;
  int t   = bt & (SEQ_T - 1);
  float acc = rdf(cb, cboff + d, bf);
#pragma unroll
  for (int k = 0; k < D_CONV; k++) {
    int tt = t + k - (D_CONV - 1);
    if (tt >= 0)
      acc += xz[(size_t)(bt + k - (D_CONV - 1)) * (2 * D_INNER) + d]
           * rdf(cw, cwoff + (long)d * D_CONV + k, bf);
  }
  float sig = 1.f / (1.f + __expf(-acc));
  u[gid] = f2b(acc * sig);
}

// ---------------------------------------------------------------------------
// x_dbl[t,0:64] = u[t,:] @ W_xp^T  (K=1024, N=64). One block per token.
// ---------------------------------------------------------------------------
__global__ __launch_bounds__(256) void xdbl_k(const bf16* __restrict__ u,
                                              const bf16* __restrict__ Warena,
                                              const void* __restrict__ Wraw, long woff,
                                              float* __restrict__ xd,
                                              const int* __restrict__ dflag)
{
  int bf = *dflag;
  const bf16* Wxp = bf ? ((const bf16*)Wraw + woff) : Warena;
  int t = blockIdx.x;
  __shared__ float us[D_INNER];
  __shared__ float red[256];
  for (int i = threadIdx.x; i < D_INNER; i += 256)
    us[i] = b2f(u[(size_t)t * D_INNER + i]);
  __syncthreads();
  int j = threadIdx.x >> 2, p = threadIdx.x & 3;
  const bf16x8* wr = (const bf16x8*)(Wxp + (size_t)j * D_INNER + p * 256);
  float s = 0.f;
#pragma unroll 4
  for (int c = 0; c < 32; c++) {
    bf16x8 wv = wr[c];
    int k = p * 256 + c * 8;
#pragma unroll
    for (int e = 0; e < 8; e++) s += us[k + e] * b2f(wv[e]);
  }
  red[threadIdx.x] = s;
  __syncthreads();
  if (p == 0)
    xd[(size_t)t * 64 + j] = red[threadIdx.x] + red[threadIdx.x + 1]
                           + red[threadIdx.x + 2] + red[threadIdx.x + 3];
}

// ---------------------------------------------------------------------------
// dt[t,d] = softplus(x_dbl[t,0:32] @ W_dt[d,:]^T + b_dt[d])   (K=32)
// ---------------------------------------------------------------------------
__global__ __launch_bounds__(256) void dt_k(const float* __restrict__ xd,
                                            const bf16* __restrict__ Warena,
                                            const void* __restrict__ Wraw, long woff,
                                            const void* __restrict__ bdt, long boff,
                                            float* __restrict__ dtb,
                                            const int* __restrict__ dflag)
{
  int bf = *dflag;
  const bf16* Wdt = bf ? ((const bf16*)Wraw + woff) : Warena;
  int t = blockIdx.x >> 2;
  int d = ((blockIdx.x & 3) << 8) + threadIdx.x;
  __shared__ float xr[DT_RANK];
  if (threadIdx.x < DT_RANK) xr[threadIdx.x] = xd[(size_t)t * 64 + threadIdx.x];
  __syncthreads();
  float s = rdf(bdt, boff + d, bf);
  const bf16x8* wr = (const bf16x8*)(Wdt + (size_t)d * DT_RANK);
#pragma unroll
  for (int c = 0; c < 4; c++) {
    bf16x8 wv = wr[c];
#pragma unroll
    for (int e = 0; e < 8; e++) s += xr[c * 8 + e] * b2f(wv[e]);
  }
  s = (s > 20.f) ? s : log1pf(__expf(s));
  dtb[(size_t)t * D_INNER + d] = s;
}

// ---------------------------------------------------------------------------
// Chunked selective scan.
// The recurrence h[t] = dA[t]*h[t-1] + x[t] is first-order linear, so a
// chunk of CHUNK steps composes to h_out = P*h_in + Q. Three phases:
//   A: per (b,d,s,chunk) compute P = prod dA, Q = chunk scan from h=0
//      (grid 2048 blocks -> 8192 waves -> full occupancy, depth 64)
//   B: tiny sequential fix-up across NCHUNK composites per chain -> Hin
//   C: re-run recurrence per chunk from Hin, emit y (full occupancy)
// Same lane layout as before: 16 s-lanes x 16 d-channels per block.
// ---------------------------------------------------------------------------
__global__ __launch_bounds__(256) void scanA_k(const float* __restrict__ dtb,
                                               const bf16* __restrict__ u,
                                               const float* __restrict__ xd,
                                               const void* __restrict__ A_log, long aoff,
                                               float* __restrict__ Pb,
                                               float* __restrict__ Qb,
                                               const int* __restrict__ dflag)
{
  int bf = *dflag;
  int s  = threadIdx.x & 15;
  int dl = threadIdx.x >> 4;          // 0..15
  int c  = blockIdx.x & (NCHUNK - 1);
  int dg = (blockIdx.x >> 4) & 63;
  int b  = blockIdx.x >> 10;
  int d  = dg * 16 + dl;

  float Av = -__expf(rdf(A_log, aoff + (long)d * D_STATE + s, bf));
  float h = 0.f, P = 1.f;
  size_t row0 = (size_t)b * SEQ_T + (size_t)c * CHUNK;

  float dt_n = dtb[row0 * D_INNER + d];
  float u_n  = b2f(u[row0 * D_INNER + d]);
  float B_n  = xd[row0 * 64 + DT_RANK + s];

  for (int t = 0; t < CHUNK; t++) {
    float dt_v = dt_n, u_v = u_n, Bv = B_n;
    if (t + 1 < CHUNK) {
      size_t r1 = row0 + t + 1;
      dt_n = dtb[r1 * D_INNER + d];
      u_n  = b2f(u[r1 * D_INNER + d]);
      B_n  = xd[r1 * 64 + DT_RANK + s];
    }
    float dA = __expf(dt_v * Av);
    P *= dA;
    h = dA * h + (dt_v * u_v) * Bv;
  }
  size_t o = (((size_t)b * D_INNER + d) * D_STATE + s) * NCHUNK + c;
  Pb[o] = P;
  Qb[o] = h;
}

__global__ __launch_bounds__(256) void scanB_k(const float* __restrict__ Pb,
                                               const float* __restrict__ Qb,
                                               float* __restrict__ Hin)
{
  int tid = blockIdx.x * 256 + threadIdx.x;   // one per (b,d,s)
  size_t base = (size_t)tid * NCHUNK;
  float h = 0.f;
#pragma unroll
  for (int c = 0; c < NCHUNK; c++) {
    Hin[base + c] = h;
    h = Pb[base + c] * h + Qb[base + c];
  }
}

__global__ __launch_bounds__(256) void scanC_k(const float* __restrict__ dtb,
                                               const bf16* __restrict__ u,
                                               const float* __restrict__ xd,
                                               const float* __restrict__ xz,
                                               const void* __restrict__ A_log, long aoff,
                                               const void* __restrict__ D_p, long doff,
                                               const float* __restrict__ Hin,
                                               bf16* __restrict__ y,
                                               const int* __restrict__ dflag)
{
  int bf = *dflag;
  int s  = threadIdx.x & 15;
  int dl = threadIdx.x >> 4;
  int c  = blockIdx.x & (NCHUNK - 1);
  int dg = (blockIdx.x >> 4) & 63;
  int b  = blockIdx.x >> 10;
  int d  = dg * 16 + dl;

  float Av = -__expf(rdf(A_log, aoff + (long)d * D_STATE + s, bf));
  float Dv = rdf(D_p, doff + d, bf);
  float h  = Hin[(((size_t)b * D_INNER + d) * D_STATE + s) * NCHUNK + c];
  size_t row0 = (size_t)b * SEQ_T + (size_t)c * CHUNK;

  float dt_n = dtb[row0 * D_INNER + d];
  float u_n  = b2f(u[row0 * D_INNER + d]);
  float B_n  = xd[row0 * 64 + DT_RANK + s];
  float C_n  = xd[row0 * 64 + DT_RANK + D_STATE + s];

  for (int t = 0; t < CHUNK; t++) {
    float dt_v = dt_n, u_v = u_n, Bv = B_n, Cv = C_n;
    if (t + 1 < CHUNK) {
      size_t r1 = row0 + t + 1;
      dt_n = dtb[r1 * D_INNER + d];
      u_n  = b2f(u[r1 * D_INNER + d]);
      B_n  = xd[r1 * 64 + DT_RANK + s];
      C_n  = xd[r1 * 64 + DT_RANK + D_STATE + s];
    }
    float dA = __expf(dt_v * Av);
    h = dA * h + (dt_v * u_v) * Bv;
    float p = h * Cv;
    p += __shfl_xor(p, 1);
    p += __shfl_xor(p, 2);
    p += __shfl_xor(p, 4);
    p += __shfl_xor(p, 8);
    if (s == 0) {
      size_t r = row0 + t;
      float zv  = xz[r * (2 * D_INNER) + D_INNER + d];
      float sig = 1.f / (1.f + __expf(-zv));
      y[r * D_INNER + d] = f2b((p + u_v * Dv) * (zv * sig));
    }
  }
}

// ---------------------------------------------------------------------------
__global__ void cast_k(const float* __restrict__ x, bf16* __restrict__ o, int n)
{
  int i = blockIdx.x * 256 + threadIdx.x;
  if (i < n) o[i] = f2b(x[i]);
}

// ---------------------------------------------------------------------------
extern "C" void kernel_launch(void* const* d_in, const int* in_sizes, int n_in,
                              void* d_out, int out_size, void* d_ws, size_t ws_size,
                              hipStream_t stream)
{
  const int* idx = (const int*)d_in[0];
  const void* tok    = d_in[1];
  const void* pos    = d_in[2];
  const void* ln1_g  = d_in[3];
  const void* ln1_b  = d_in[4];
  const void* W_in   = d_in[5];
  const void* conv_w = d_in[6];
  const void* conv_b = d_in[7];
  const void* W_xp   = d_in[8];
  const void* W_dt   = d_in[9];
  const void* b_dt   = d_in[10];
  const void* A_log  = d_in[11];
  const void* D_p    = d_in[12];
  const void* W_out  = d_in[13];
  const void* ln2_g  = d_in[14];
  const void* ln2_b  = d_in[15];
  const void* W_f1   = d_in[16];
  const void* b_f1   = d_in[17];
  const void* W_f2   = d_in[18];
  const void* b_f2   = d_in[19];
  const void* lm_w   = d_in[20];
  const void* lm_b   = d_in[21];

  char* ws = (char*)d_ws;
  int*  dflag = (int*)ws;    ws += 256;
  float* x_res = (float*)ws; ws += (size_t)BT * D_MODEL * 4;
  float* xz    = (float*)ws; ws += (size_t)BT * 2 * D_INNER * 4;
  float* xdbl  = (float*)ws; ws += (size_t)BT * 64 * 4;
  float* dtb   = (float*)ws; ws += (size_t)BT * D_INNER * 4;
  bf16* lnbuf  = (bf16*)ws;  ws += (size_t)BT * D_MODEL * 2;
  bf16* ubuf   = (bf16*)ws;  ws += (size_t)BT * D_INNER * 2;
  bf16* ybuf   = (bf16*)ws;  ws += (size_t)BT * D_INNER * 2;
  bf16* hbuf   = (bf16*)ws;  ws += (size_t)BT * H_FFN * 2;
  // chunked-scan composites: [B, D_INNER, D_STATE, NCHUNK] f32 each
  float* Pbuf  = (float*)ws; ws += (size_t)BATCH * D_INNER * D_STATE * NCHUNK * 4;
  float* Qbuf  = (float*)ws; ws += (size_t)BATCH * D_INNER * D_STATE * NCHUNK * 4;
  float* Hin   = (float*)ws; ws += (size_t)BATCH * D_INNER * D_STATE * NCHUNK * 4;
  // bf16 canonical weight arena (filled only when inputs are f32)
  bf16* aW_in  = (bf16*)ws;  ws += (size_t)N_LAYER * 2*D_INNER * D_MODEL * 2;
  bf16* aW_xp  = (bf16*)ws;  ws += (size_t)N_LAYER * 64 * D_INNER * 2;
  bf16* aW_dt  = (bf16*)ws;  ws += (size_t)N_LAYER * D_INNER * DT_RANK * 2;
  bf16* aW_out = (bf16*)ws;  ws += (size_t)N_LAYER * D_MODEL * D_INNER * 2;
  bf16* aW_f1  = (bf16*)ws;  ws += (size_t)N_LAYER * H_FFN * D_MODEL * 2;
  bf16* aW_f2  = (bf16*)ws;  ws += (size_t)N_LAYER * D_MODEL * H_FFN * 2;
  bf16* aLm    = (bf16*)ws;  ws += (size_t)VOCAB * D_MODEL * 2;

  probe_k<<<1, 64, 0, stream>>>((const unsigned short*)tok,
                                (const unsigned short*)pos, dflag);

  auto cvt = [&](const void* src, bf16* dst, long n) {
    int n4 = (int)(n / 4);
    cvt_k<<<(n4 + 255) / 256, 256, 0, stream>>>((const float4*)src, dst, n4, dflag);
  };
  cvt(W_in,  aW_in,  (long)N_LAYER * 2*D_INNER * D_MODEL);
  cvt(W_xp,  aW_xp,  (long)N_LAYER * 64 * D_INNER);
  cvt(W_dt,  aW_dt,  (long)N_LAYER * D_INNER * DT_RANK);
  cvt(W_out, aW_out, (long)N_LAYER * D_MODEL * D_INNER);
  cvt(W_f1,  aW_f1,  (long)N_LAYER * H_FFN * D_MODEL);
  cvt(W_f2,  aW_f2,  (long)N_LAYER * D_MODEL * H_FFN);
  cvt(lm_w,  aLm,    (long)VOCAB * D_MODEL);

  embed_k<<<BT, 256, 0, stream>>>(idx, tok, pos, x_res, dflag);

  for (int l = 0; l < N_LAYER; l++) {
    long oWin = (long)l * 2*D_INNER * D_MODEL;
    long oWxp = (long)l * 64 * D_INNER;
    long oWdt = (long)l * D_INNER * DT_RANK;
    long oWo  = (long)l * D_MODEL * D_INNER;
    long oWf1 = (long)l * H_FFN * D_MODEL;
    long oWf2 = (long)l * D_MODEL * H_FFN;
    long oA   = (long)l * D_INNER * D_STATE;
    long oD   = (long)l * D_INNER;

    ln_k<<<BT, 64, 0, stream>>>(x_res, ln1_g, ln1_b, (long)l * D_MODEL, lnbuf, dflag);

    gemm_nt<0, false><<<dim3(2 * D_INNER / 128, BT / 128), 256, 0, stream>>>(
        lnbuf, aW_in + oWin, W_in, oWin, xz, nullptr, 0, nullptr, dflag,
        BT, 2 * D_INNER, D_MODEL);

    conv_silu_k<<<BT * D_INNER / 256, 256, 0, stream>>>(
        xz, conv_w, conv_b, (long)l * D_INNER * D_CONV, oD, ubuf, dflag);

    xdbl_k<<<BT, 256, 0, stream>>>(ubuf, aW_xp + oWxp, W_xp, oWxp, xdbl, dflag);

    dt_k<<<BT * 4, 256, 0, stream>>>(
        xdbl, aW_dt + oWdt, W_dt, oWdt, b_dt, oD, dtb, dflag);

    scanA_k<<<BATCH * 64 * NCHUNK, 256, 0, stream>>>(
        dtb, ubuf, xdbl, A_log, oA, Pbuf, Qbuf, dflag);
    scanB_k<<<BATCH * D_INNER * D_STATE / 256, 256, 0, stream>>>(Pbuf, Qbuf, Hin);
    scanC_k<<<BATCH * 64 * NCHUNK, 256, 0, stream>>>(
        dtb, ubuf, xdbl, xz, A_log, oA, D_p, oD, Hin, ybuf, dflag);

    gemm_nt<0, false><<<dim3(D_MODEL / 128, BT / 128), 256, 0, stream>>>(
        ybuf, aW_out + oWo, W_out, oWo, x_res, nullptr, 0, x_res, dflag,
        BT, D_MODEL, D_INNER);

    ln_k<<<BT, 64, 0, stream>>>(x_res, ln2_g, ln2_b, (long)l * D_MODEL, lnbuf, dflag);

    gemm_nt<1, true><<<dim3(H_FFN / 128, BT / 128), 256, 0, stream>>>(
        lnbuf, aW_f1 + oWf1, W_f1, oWf1, hbuf, b_f1, (long)l * H_FFN, nullptr, dflag,
        BT, H_FFN, D_MODEL);

    gemm_nt<0, false><<<dim3(D_MODEL / 128, BT / 128), 256, 0, stream>>>(
        hbuf, aW_f2 + oWf2, W_f2, oWf2, x_res, b_f2, (long)l * D_MODEL, x_res, dflag,
        BT, D_MODEL, H_FFN);
  }

  cast_k<<<BT * D_MODEL / 256, 256, 0, stream>>>(x_res, lnbuf, BT * D_MODEL);

  gemm_nt<2, false><<<dim3(VOCAB / 128, BT / 128), 256, 0, stream>>>(
      lnbuf, aLm, lm_w, 0, d_out, lm_b, 0, nullptr, dflag,
      BT, VOCAB, D_MODEL);
}